// Round 1
// baseline (1085.805 us; speedup 1.0000x reference)
//
#include <hip/hip_runtime.h>
#include <stdint.h>

typedef unsigned short u16;
typedef __bf16 bf16x8 __attribute__((ext_vector_type(8)));
typedef float f32x4 __attribute__((ext_vector_type(4)));
typedef unsigned short u16x8 __attribute__((ext_vector_type(8)));
typedef unsigned short u16x4 __attribute__((ext_vector_type(4)));
typedef __attribute__((address_space(1))) unsigned int gu32;
typedef __attribute__((address_space(3))) unsigned int lu32;

__device__ __forceinline__ float bf2f(u16 u){ unsigned int v=((unsigned int)u)<<16; float f; __builtin_memcpy(&f,&v,4); return f; }
__device__ __forceinline__ u16 f2bf(float f){ unsigned int v; __builtin_memcpy(&v,&f,4); v += 0x7fffu + ((v>>16)&1u); return (u16)(v>>16); }
__device__ __forceinline__ int swz(int r,int c){ return (r<<6) + (c ^ ((r&7)<<3)); }
__device__ __forceinline__ void glds16(const void* g, void* l){
  __builtin_amdgcn_global_load_lds((gu32*)g, (lu32*)l, 16, 0, 0);
}

// ---------------- casts ----------------
__global__ __launch_bounds__(256) void k_cast(const float* __restrict__ in, u16* __restrict__ out, int n4){
  int i = blockIdx.x*256 + threadIdx.x;
  if (i >= n4) return;
  const f32x4 v = *(const f32x4*)(in + (size_t)i*4);
  u16x4 o; o.x=f2bf(v.x); o.y=f2bf(v.y); o.z=f2bf(v.z); o.w=f2bf(v.w);
  *(u16x4*)(out + (size_t)i*4) = o;
}

__global__ __launch_bounds__(256) void k_cast_pad(const float* __restrict__ in, u16* __restrict__ out){
  int i = blockIdx.x*256 + threadIdx.x;       // 4 elems each over 3328x768
  int e0 = i*4;
  int row = e0 / 768;
  int col = e0 - row*768;
  u16x4 o;
  if (row < 3224){
    const f32x4 v = *(const f32x4*)(in + (size_t)row*768 + col);
    o.x=f2bf(v.x); o.y=f2bf(v.y); o.z=f2bf(v.z); o.w=f2bf(v.w);
  } else { o.x=0; o.y=0; o.z=0; o.w=0; }
  *(u16x4*)(out + e0) = o;
}

// ---------------- bf16 GEMM (A:MxK rm, Bw:NxK rm), 128x128 tile ----------------
template<int K, int EPI>
__global__ __launch_bounds__(256,2) void k_gemm(
    const u16* __restrict__ A, const u16* __restrict__ Bw,
    u16* __restrict__ o_z, u16* __restrict__ o_xbc, float* __restrict__ o_dt,
    const float* __restrict__ dt_bias, float* __restrict__ o_f32)
{
  __shared__ __align__(16) u16 Alds[8192];
  __shared__ __align__(16) u16 Blds[8192];
  const int tid = threadIdx.x;
  const int wave = tid>>6, lane = tid&63;
  const int m0 = blockIdx.x<<7, n0 = blockIdx.y<<7;
  const int wr = (wave>>1)<<6, wc = (wave&1)<<6;
  const int srow = tid>>3, sc0 = (tid&7)<<3;
  const int lo16 = lane&15, hi = lane>>4;
  f32x4 acc[4][4] = {};
  for (int k0 = 0; k0 < K; k0 += 64){
    #pragma unroll
    for (int i = 0; i < 4; ++i){
      const int row = (i<<5) + srow;
      const int scol = sc0 ^ ((row&7)<<3);
      glds16(A  + (size_t)(m0+row)*K + k0 + scol, &Alds[(i<<11) + (wave<<9)]);
      glds16(Bw + (size_t)(n0+row)*K + k0 + scol, &Blds[(i<<11) + (wave<<9)]);
    }
    __syncthreads();
    #pragma unroll
    for (int kk = 0; kk < 2; ++kk){
      const int kb = (kk<<5) + (hi<<3);
      bf16x8 af[4], bfv[4];
      #pragma unroll
      for (int m = 0; m < 4; ++m){
        const int r = wr + (m<<4) + lo16;
        af[m] = *(const bf16x8*)&Alds[(r<<6) + (kb ^ ((r&7)<<3))];
      }
      #pragma unroll
      for (int n = 0; n < 4; ++n){
        const int r = wc + (n<<4) + lo16;
        bfv[n] = *(const bf16x8*)&Blds[(r<<6) + (kb ^ ((r&7)<<3))];
      }
      #pragma unroll
      for (int m = 0; m < 4; ++m)
      #pragma unroll
      for (int n = 0; n < 4; ++n)
        acc[m][n] = __builtin_amdgcn_mfma_f32_16x16x32_bf16(af[m], bfv[n], acc[m][n], 0,0,0);
    }
    __syncthreads();
  }
  #pragma unroll
  for (int m = 0; m < 4; ++m)
  #pragma unroll
  for (int n = 0; n < 4; ++n)
  #pragma unroll
  for (int i = 0; i < 4; ++i){
    const int gr = m0 + wr + (m<<4) + (hi<<2) + i;
    const int gc = n0 + wc + (n<<4) + lo16;
    const float v = acc[m][n][i];
    if constexpr (EPI == 0){
      if (gc < 1536)      o_z[(size_t)gr*1536 + gc] = f2bf(v);
      else if (gc < 3200) o_xbc[(size_t)gr*1664 + (gc-1536)] = f2bf(v);
      else if (gc < 3224){
        const float t = v + dt_bias[gc-3200];
        o_dt[(size_t)gr*24 + (gc-3200)] = (t > 20.f) ? t : log1pf(__expf(t));
      }
    } else {
      o_f32[(size_t)gr*768 + gc] = v;
    }
  }
}

// ---------------- depthwise causal conv(4) + SiLU + split ----------------
__global__ __launch_bounds__(256) void k_conv(
    const u16* __restrict__ xbc, const float* __restrict__ cw, const float* __restrict__ cb,
    u16* __restrict__ xo, u16* __restrict__ Bo, u16* __restrict__ Co)
{
  const int idx = blockIdx.x*256 + threadIdx.x;
  if (idx >= 32768*208) return;
  const int m = idx / 208;
  const int ch0 = (idx - m*208) << 3;
  const int l = m & 4095;
  float acc[8];
  #pragma unroll
  for (int j = 0; j < 8; ++j) acc[j] = cb[ch0+j];
  #pragma unroll
  for (int t = 0; t < 4; ++t){
    const int ls = l - 3 + t;
    if (ls < 0) continue;
    const u16x8 v = *(const u16x8*)(xbc + (size_t)(m-3+t)*1664 + ch0);
    #pragma unroll
    for (int j = 0; j < 8; ++j) acc[j] += bf2f(v[j]) * cw[(ch0+j)*4 + t];
  }
  u16x8 o;
  #pragma unroll
  for (int j = 0; j < 8; ++j){ const float s = acc[j]; o[j] = f2bf(s / (1.f + __expf(-s))); }
  if (ch0 < 1536)      *(u16x8*)(xo + (size_t)m*1536 + ch0)      = o;
  else if (ch0 < 1600) *(u16x8*)(Bo + (size_t)m*64 + (ch0-1536)) = o;
  else                 *(u16x8*)(Co + (size_t)m*64 + (ch0-1600)) = o;
}

// ---------------- fused chunked SSD: one block per (b,h) ----------------
__global__ __launch_bounds__(256,1) void k_ssd(
    const u16* __restrict__ xc, const u16* __restrict__ Bg, const u16* __restrict__ Cg,
    const float* __restrict__ dtg, const float* __restrict__ A_log,
    const float* __restrict__ Dp, u16* __restrict__ yo)
{
  __shared__ __align__(16) u16 Bn[4096], Bdt[4096], Cn[4096], Cd[4096], xdtT[4096], xls[4096], Ml[4096], Sbf[4096];
  __shared__ float Sst[4096];
  __shared__ float df[64], Acs[64];
  const int tid = threadIdx.x, wave = tid>>6, lane = tid&63;
  const int lo16 = lane&15, hi = lane>>4;
  const int b = blockIdx.x / 24, h = blockIdx.x % 24;
  const float Ah = -__expf(A_log[h]);
  const float Dh = Dp[h];
  for (int i = tid; i < 4096; i += 256){ Sst[i]=0.f; Sbf[i]=0; }
  const int lrow = tid>>2, c16 = (tid&3)<<4;
  const size_t bx  = (size_t)b*4096*1536 + (size_t)h*64;
  const size_t bbc = (size_t)b*4096*64;
  const size_t bdt = (size_t)b*4096*24 + h;

  for (int c = 0; c < 64; ++c){
    const int l0 = c<<6;
    if (tid < 64) df[tid] = dtg[bdt + (size_t)(l0+tid)*24];
    __syncthreads();
    if (wave == 0){
      float s = Ah * df[lane];
      #pragma unroll
      for (int off = 1; off < 64; off <<= 1){
        const float t = __shfl_up(s, off);
        if (lane >= off) s += t;
      }
      Acs[lane] = s;
    }
    __syncthreads();
    const float Alast = Acs[63];
    {
      const float dtl = df[lrow];
      const float dec = __expf(Alast - Acs[lrow]);
      const float el  = __expf(Acs[lrow]);
      const u16* gx  = xc + bx  + (size_t)(l0+lrow)*1536 + c16;
      const u16* gb  = Bg + bbc + (size_t)(l0+lrow)*64 + c16;
      const u16* gcp = Cg + bbc + (size_t)(l0+lrow)*64 + c16;
      const u16x8 x0 = *(const u16x8*)gx;      const u16x8 x1 = *(const u16x8*)(gx+8);
      const u16x8 b0 = *(const u16x8*)gb;      const u16x8 b1 = *(const u16x8*)(gb+8);
      const u16x8 c0 = *(const u16x8*)gcp;     const u16x8 c1 = *(const u16x8*)(gcp+8);
      #pragma unroll
      for (int j = 0; j < 8; ++j){
        const int p = c16 + j, q = c16 + 8 + j;
        xls[swz(lrow,p)]  = x0[j];                         xls[swz(lrow,q)]  = x1[j];
        xdtT[swz(p,lrow)] = f2bf(bf2f(x0[j]) * dtl);       xdtT[swz(q,lrow)] = f2bf(bf2f(x1[j]) * dtl);
        Bn[swz(lrow,p)]   = b0[j];                         Bn[swz(lrow,q)]   = b1[j];
        Bdt[swz(p,lrow)]  = f2bf(bf2f(b0[j]) * dec);       Bdt[swz(q,lrow)]  = f2bf(bf2f(b1[j]) * dec);
        Cn[swz(lrow,p)]   = c0[j];                         Cn[swz(lrow,q)]   = c1[j];
        Cd[swz(lrow,p)]   = f2bf(bf2f(c0[j]) * el);        Cd[swz(lrow,q)]   = f2bf(bf2f(c1[j]) * el);
      }
    }
    __syncthreads();
    // G = C . B^T  (wave owns rows [wave*16, wave*16+16))
    f32x4 accG[4] = {};
    #pragma unroll
    for (int kk = 0; kk < 2; ++kk){
      const int kb = (kk<<5) + (hi<<3);
      const int rA = (wave<<4) + lo16;
      const bf16x8 a = *(const bf16x8*)&Cn[(rA<<6) + (kb ^ ((rA&7)<<3))];
      #pragma unroll
      for (int t = 0; t < 4; ++t){
        const int rb = (t<<4) + lo16;
        const bf16x8 bb = *(const bf16x8*)&Bn[(rb<<6) + (kb ^ ((rb&7)<<3))];
        accG[t] = __builtin_amdgcn_mfma_f32_16x16x32_bf16(a, bb, accG[t], 0,0,0);
      }
    }
    // M = mask(G) * exp(Acs[r]-Acs[s])  -> wave-private rows, no barrier needed
    #pragma unroll
    for (int t = 0; t < 4; ++t)
    #pragma unroll
    for (int i = 0; i < 4; ++i){
      const int r = (wave<<4) + (hi<<2) + i;
      const int s = (t<<4) + lo16;
      const float v = (s <= r) ? accG[t][i] * __expf(Acs[r] - Acs[s]) : 0.f;
      Ml[swz(r,s)] = f2bf(v);
    }
    // Y = M.xdt + Cd.S^T ;  S_chunk = xdtT.(dec*B)
    f32x4 accY[4] = {}, accS[4] = {};
    #pragma unroll
    for (int kk = 0; kk < 2; ++kk){
      const int kb = (kk<<5) + (hi<<3);
      const int rA = (wave<<4) + lo16;
      const int oA = (rA<<6) + (kb ^ ((rA&7)<<3));
      const bf16x8 aM = *(const bf16x8*)&Ml[oA];
      const bf16x8 aC = *(const bf16x8*)&Cd[oA];
      const bf16x8 aX = *(const bf16x8*)&xdtT[oA];
      #pragma unroll
      for (int t = 0; t < 4; ++t){
        const int rb = (t<<4) + lo16;
        const int o = (rb<<6) + (kb ^ ((rb&7)<<3));
        const bf16x8 bX = *(const bf16x8*)&xdtT[o];
        const bf16x8 bS = *(const bf16x8*)&Sbf[o];
        const bf16x8 bB = *(const bf16x8*)&Bdt[o];
        accY[t] = __builtin_amdgcn_mfma_f32_16x16x32_bf16(aM, bX, accY[t], 0,0,0);
        accY[t] = __builtin_amdgcn_mfma_f32_16x16x32_bf16(aC, bS, accY[t], 0,0,0);
        accS[t] = __builtin_amdgcn_mfma_f32_16x16x32_bf16(aX, bB, accS[t], 0,0,0);
      }
    }
    __syncthreads();   // all waves done reading Sbf before update
    const float lam = __expf(Alast);
    #pragma unroll
    for (int t = 0; t < 4; ++t)
    #pragma unroll
    for (int i = 0; i < 4; ++i){
      const int p = (wave<<4) + (hi<<2) + i;
      const int n = (t<<4) + lo16;
      const float s = Sst[(p<<6)+n] * lam + accS[t][i];
      Sst[(p<<6)+n] = s;
      Sbf[swz(p,n)] = f2bf(s);
    }
    #pragma unroll
    for (int t = 0; t < 4; ++t)
    #pragma unroll
    for (int i = 0; i < 4; ++i){
      const int r = (wave<<4) + (hi<<2) + i;
      const int p = (t<<4) + lo16;
      const float y = accY[t][i] + bf2f(xls[swz(r,p)]) * Dh;
      yo[bx + (size_t)(l0+r)*1536 + p] = f2bf(y);
    }
  }
}

// ---------------- gate (silu(z)) + RMS norm ----------------
__global__ __launch_bounds__(192) void k_gnorm(
    const u16* __restrict__ y, const u16* __restrict__ z,
    const float* __restrict__ nw, u16* __restrict__ out)
{
  __shared__ float red[3];
  const int m = blockIdx.x, t = threadIdx.x;
  const size_t base = (size_t)m*1536 + t*8;
  const u16x8 yv = *(const u16x8*)(y + base);
  const u16x8 zv = *(const u16x8*)(z + base);
  float vals[8]; float ss = 0.f;
  #pragma unroll
  for (int j = 0; j < 8; ++j){
    const float zf = bf2f(zv[j]);
    const float v = bf2f(yv[j]) * zf / (1.f + __expf(-zf));
    vals[j] = v; ss += v*v;
  }
  #pragma unroll
  for (int off = 32; off > 0; off >>= 1) ss += __shfl_down(ss, off);
  if ((t & 63) == 0) red[t>>6] = ss;
  __syncthreads();
  const float sc = rsqrtf((red[0]+red[1]+red[2]) * (1.f/1536.f) + 1e-5f);
  u16x8 o;
  #pragma unroll
  for (int j = 0; j < 8; ++j) o[j] = f2bf(vals[j] * sc * nw[t*8+j]);
  *(u16x8*)(out + base) = o;
}

extern "C" void kernel_launch(void* const* d_in, const int* in_sizes, int n_in,
                              void* d_out, int out_size, void* d_ws, size_t ws_size,
                              hipStream_t stream)
{
  const float* u       = (const float*)d_in[0];
  const float* W_in    = (const float*)d_in[1];
  const float* conv_w  = (const float*)d_in[2];
  const float* conv_b  = (const float*)d_in[3];
  const float* dt_bias = (const float*)d_in[4];
  const float* A_log   = (const float*)d_in[5];
  const float* D_param = (const float*)d_in[6];
  const float* norm_w  = (const float*)d_in[7];
  const float* W_out   = (const float*)d_in[8];
  (void)in_sizes; (void)n_in; (void)out_size;
  if (ws_size < (size_t)379715584) return;   // clean fail instead of corruption

  char* w = (char*)d_ws;
  size_t off = 0;
  auto alloc = [&](size_t bytes)->void*{ void* p = w + off; off += (bytes + 255) & ~(size_t)255; return p; };
  u16* ubf    = (u16*)alloc(50331648);    // 32768x768 bf16
  u16* winbf  = (u16*)alloc(5111808);     // 3328x768 bf16 (padded)
  u16* woutbf = (u16*)alloc(2359296);     // 768x1536 bf16
  u16* zbf    = (u16*)alloc(100663296);   // 32768x1536 bf16
  u16* xbcbf  = (u16*)alloc(109051904);   // 32768x1664 bf16 (reused as yssd)
  float* dtbuf= (float*)alloc(3145728);   // 32768x24 f32
  u16* xconv  = (u16*)alloc(100663296);   // 32768x1536 bf16 (reused as ynorm)
  u16* Bbuf   = (u16*)alloc(4194304);     // 32768x64 bf16
  u16* Cbuf   = (u16*)alloc(4194304);     // 32768x64 bf16
  u16* yssd   = xbcbf;
  u16* ynorm  = xconv;

  k_cast<<<24576, 256, 0, stream>>>(u, ubf, 6291456);
  k_cast_pad<<<2496, 256, 0, stream>>>(W_in, winbf);
  k_cast<<<1152, 256, 0, stream>>>(W_out, woutbf, 294912);
  k_gemm<768,0><<<dim3(256,26), 256, 0, stream>>>(ubf, winbf, zbf, xbcbf, dtbuf, dt_bias, nullptr);
  k_conv<<<26624, 256, 0, stream>>>(xbcbf, conv_w, conv_b, xconv, Bbuf, Cbuf);
  k_ssd<<<192, 256, 0, stream>>>(xconv, Bbuf, Cbuf, dtbuf, A_log, D_param, yssd);
  k_gnorm<<<32768, 192, 0, stream>>>(yssd, zbf, norm_w, ynorm);
  k_gemm<1536,1><<<dim3(256,6), 256, 0, stream>>>(ynorm, woutbf, nullptr, nullptr, nullptr, nullptr, (float*)d_out);
}

// Round 2
// 752.411 us; speedup vs baseline: 1.4431x; 1.4431x over previous
//
#include <hip/hip_runtime.h>
#include <stdint.h>

typedef unsigned short u16;
typedef __bf16 bf16x8 __attribute__((ext_vector_type(8)));
typedef float f32x4 __attribute__((ext_vector_type(4)));
typedef unsigned short u16x8 __attribute__((ext_vector_type(8)));
typedef unsigned short u16x4 __attribute__((ext_vector_type(4)));
typedef __attribute__((address_space(1))) unsigned int gu32;
typedef __attribute__((address_space(3))) unsigned int lu32;

__device__ __forceinline__ float bf2f(u16 u){ unsigned int v=((unsigned int)u)<<16; float f; __builtin_memcpy(&f,&v,4); return f; }
__device__ __forceinline__ u16 f2bf(float f){ unsigned int v; __builtin_memcpy(&v,&f,4); v += 0x7fffu + ((v>>16)&1u); return (u16)(v>>16); }
__device__ __forceinline__ int swz(int r,int c){ return (r<<6) + (c ^ ((r&7)<<3)); }
__device__ __forceinline__ void glds16(const void* g, void* l){
  __builtin_amdgcn_global_load_lds((gu32*)g, (lu32*)l, 16, 0, 0);
}

// ---------------- casts ----------------
__global__ __launch_bounds__(256) void k_cast(const float* __restrict__ in, u16* __restrict__ out, int n4){
  int i = blockIdx.x*256 + threadIdx.x;
  if (i >= n4) return;
  const f32x4 v = *(const f32x4*)(in + (size_t)i*4);
  u16x4 o; o.x=f2bf(v.x); o.y=f2bf(v.y); o.z=f2bf(v.z); o.w=f2bf(v.w);
  *(u16x4*)(out + (size_t)i*4) = o;
}

__global__ __launch_bounds__(256) void k_cast_pad(const float* __restrict__ in, u16* __restrict__ out){
  int i = blockIdx.x*256 + threadIdx.x;       // 4 elems each over 3328x768
  int e0 = i*4;
  int row = e0 / 768;
  int col = e0 - row*768;
  u16x4 o;
  if (row < 3224){
    const f32x4 v = *(const f32x4*)(in + (size_t)row*768 + col);
    o.x=f2bf(v.x); o.y=f2bf(v.y); o.z=f2bf(v.z); o.w=f2bf(v.w);
  } else { o.x=0; o.y=0; o.z=0; o.w=0; }
  *(u16x4*)(out + e0) = o;
}

// ---------------- bf16 GEMM (A:MxK rm, Bw:NxK rm), 128x128 tile ----------------
template<int K, int EPI>
__global__ __launch_bounds__(256,2) void k_gemm(
    const u16* __restrict__ A, const u16* __restrict__ Bw,
    u16* __restrict__ o_z, u16* __restrict__ o_xbc, float* __restrict__ o_dt,
    const float* __restrict__ dt_bias, float* __restrict__ o_f32)
{
  __shared__ __align__(16) u16 Alds[8192];
  __shared__ __align__(16) u16 Blds[8192];
  const int tid = threadIdx.x;
  const int wave = tid>>6, lane = tid&63;
  const int m0 = blockIdx.x<<7, n0 = blockIdx.y<<7;
  const int wr = (wave>>1)<<6, wc = (wave&1)<<6;
  const int srow = tid>>3, sc0 = (tid&7)<<3;
  const int lo16 = lane&15, hi = lane>>4;
  f32x4 acc[4][4] = {};
  for (int k0 = 0; k0 < K; k0 += 64){
    #pragma unroll
    for (int i = 0; i < 4; ++i){
      const int row = (i<<5) + srow;
      const int scol = sc0 ^ ((row&7)<<3);
      glds16(A  + (size_t)(m0+row)*K + k0 + scol, &Alds[(i<<11) + (wave<<9)]);
      glds16(Bw + (size_t)(n0+row)*K + k0 + scol, &Blds[(i<<11) + (wave<<9)]);
    }
    __syncthreads();
    #pragma unroll
    for (int kk = 0; kk < 2; ++kk){
      const int kb = (kk<<5) + (hi<<3);
      bf16x8 af[4], bfv[4];
      #pragma unroll
      for (int m = 0; m < 4; ++m){
        const int r = wr + (m<<4) + lo16;
        af[m] = *(const bf16x8*)&Alds[(r<<6) + (kb ^ ((r&7)<<3))];
      }
      #pragma unroll
      for (int n = 0; n < 4; ++n){
        const int r = wc + (n<<4) + lo16;
        bfv[n] = *(const bf16x8*)&Blds[(r<<6) + (kb ^ ((r&7)<<3))];
      }
      #pragma unroll
      for (int m = 0; m < 4; ++m)
      #pragma unroll
      for (int n = 0; n < 4; ++n)
        acc[m][n] = __builtin_amdgcn_mfma_f32_16x16x32_bf16(af[m], bfv[n], acc[m][n], 0,0,0);
    }
    __syncthreads();
  }
  #pragma unroll
  for (int m = 0; m < 4; ++m)
  #pragma unroll
  for (int n = 0; n < 4; ++n)
  #pragma unroll
  for (int i = 0; i < 4; ++i){
    const int gr = m0 + wr + (m<<4) + (hi<<2) + i;
    const int gc = n0 + wc + (n<<4) + lo16;
    const float v = acc[m][n][i];
    if constexpr (EPI == 0){
      if (gc < 1536)      o_z[(size_t)gr*1536 + gc] = f2bf(v);
      else if (gc < 3200) o_xbc[(size_t)gr*1664 + (gc-1536)] = f2bf(v);
      else if (gc < 3224){
        const float t = v + dt_bias[gc-3200];
        o_dt[(size_t)gr*24 + (gc-3200)] = (t > 20.f) ? t : log1pf(__expf(t));
      }
    } else {
      o_f32[(size_t)gr*768 + gc] = v;
    }
  }
}

// ---------------- depthwise causal conv(4) + SiLU + split ----------------
// Thread = 8 channels x 8 consecutive L positions. Weights loaded ONCE per
// thread (8 contiguous f32x4) -> 32x fewer divergent address slots per output.
__global__ __launch_bounds__(256) void k_conv(
    const u16* __restrict__ xbc, const float* __restrict__ cw, const float* __restrict__ cb,
    u16* __restrict__ xo, u16* __restrict__ Bo, u16* __restrict__ Co)
{
  const int idx = blockIdx.x*256 + threadIdx.x;
  if (idx >= 4096*208) return;
  const int g  = idx % 208;          // channel group (8 channels)
  const int pt = idx / 208;          // 8-position tile
  const int ch0 = g << 3;
  const int m0 = pt << 3;            // first output row (global)
  const int l0 = m0 & 4095;          // position within batch (tiles never cross batch)
  float wgt[8][4], bias[8];
  #pragma unroll
  for (int j = 0; j < 8; ++j){
    const f32x4 wv = *(const f32x4*)(cw + (size_t)(ch0+j)*4);
    wgt[j][0]=wv.x; wgt[j][1]=wv.y; wgt[j][2]=wv.z; wgt[j][3]=wv.w;
    bias[j] = cb[ch0+j];
  }
  float acc[8][8];
  #pragma unroll
  for (int p = 0; p < 8; ++p)
  #pragma unroll
  for (int j = 0; j < 8; ++j) acc[p][j] = bias[j];
  #pragma unroll
  for (int r = -3; r < 8; ++r){
    const int ls = l0 + r;
    if (ls < 0) continue;
    const u16x8 v = *(const u16x8*)(xbc + (size_t)(m0+r)*1664 + ch0);
    float xf[8];
    #pragma unroll
    for (int j = 0; j < 8; ++j) xf[j] = bf2f(v[j]);
    #pragma unroll
    for (int t = 0; t < 4; ++t){
      const int p = r + 3 - t;     // output p uses row p-3+t
      if (p < 0 || p > 7) continue;
      #pragma unroll
      for (int j = 0; j < 8; ++j) acc[p][j] += xf[j] * wgt[j][t];
    }
  }
  #pragma unroll
  for (int p = 0; p < 8; ++p){
    u16x8 o;
    #pragma unroll
    for (int j = 0; j < 8; ++j){ const float s = acc[p][j]; o[j] = f2bf(s / (1.f + __expf(-s))); }
    const size_t m = m0 + p;
    if (ch0 < 1536)      *(u16x8*)(xo + m*1536 + ch0)      = o;
    else if (ch0 < 1600) *(u16x8*)(Bo + m*64 + (ch0-1536)) = o;
    else                 *(u16x8*)(Co + m*64 + (ch0-1600)) = o;
  }
}

// ---------------- fused chunked SSD: one block per (b,h) ----------------
__global__ __launch_bounds__(256,1) void k_ssd(
    const u16* __restrict__ xc, const u16* __restrict__ Bg, const u16* __restrict__ Cg,
    const float* __restrict__ dtg, const float* __restrict__ A_log,
    const float* __restrict__ Dp, u16* __restrict__ yo)
{
  __shared__ __align__(16) u16 Bn[4096], Bdt[4096], Cn[4096], Cd[4096], xdtT[4096], xls[4096], Ml[4096], Sbf[4096];
  __shared__ float Sst[4096];
  __shared__ float df[64], Acs[64];
  const int tid = threadIdx.x, wave = tid>>6, lane = tid&63;
  const int lo16 = lane&15, hi = lane>>4;
  const int b = blockIdx.x / 24, h = blockIdx.x % 24;
  const float Ah = -__expf(A_log[h]);
  const float Dh = Dp[h];
  for (int i = tid; i < 4096; i += 256){ Sst[i]=0.f; Sbf[i]=0; }
  const int lrow = tid>>2, c16 = (tid&3)<<4;
  const size_t bx  = (size_t)b*4096*1536 + (size_t)h*64;
  const size_t bbc = (size_t)b*4096*64;
  const size_t bdt = (size_t)b*4096*24 + h;

  for (int c = 0; c < 64; ++c){
    const int l0 = c<<6;
    if (tid < 64) df[tid] = dtg[bdt + (size_t)(l0+tid)*24];
    __syncthreads();
    if (wave == 0){
      float s = Ah * df[lane];
      #pragma unroll
      for (int off = 1; off < 64; off <<= 1){
        const float t = __shfl_up(s, off);
        if (lane >= off) s += t;
      }
      Acs[lane] = s;
    }
    __syncthreads();
    const float Alast = Acs[63];
    {
      const float dtl = df[lrow];
      const float dec = __expf(Alast - Acs[lrow]);
      const float el  = __expf(Acs[lrow]);
      const u16* gx  = xc + bx  + (size_t)(l0+lrow)*1536 + c16;
      const u16* gb  = Bg + bbc + (size_t)(l0+lrow)*64 + c16;
      const u16* gcp = Cg + bbc + (size_t)(l0+lrow)*64 + c16;
      const u16x8 x0 = *(const u16x8*)gx;      const u16x8 x1 = *(const u16x8*)(gx+8);
      const u16x8 b0 = *(const u16x8*)gb;      const u16x8 b1 = *(const u16x8*)(gb+8);
      const u16x8 c0 = *(const u16x8*)gcp;     const u16x8 c1 = *(const u16x8*)(gcp+8);
      #pragma unroll
      for (int j = 0; j < 8; ++j){
        const int p = c16 + j, q = c16 + 8 + j;
        xls[swz(lrow,p)]  = x0[j];                         xls[swz(lrow,q)]  = x1[j];
        xdtT[swz(p,lrow)] = f2bf(bf2f(x0[j]) * dtl);       xdtT[swz(q,lrow)] = f2bf(bf2f(x1[j]) * dtl);
        Bn[swz(lrow,p)]   = b0[j];                         Bn[swz(lrow,q)]   = b1[j];
        Bdt[swz(p,lrow)]  = f2bf(bf2f(b0[j]) * dec);       Bdt[swz(q,lrow)]  = f2bf(bf2f(b1[j]) * dec);
        Cn[swz(lrow,p)]   = c0[j];                         Cn[swz(lrow,q)]   = c1[j];
        Cd[swz(lrow,p)]   = f2bf(bf2f(c0[j]) * el);        Cd[swz(lrow,q)]   = f2bf(bf2f(c1[j]) * el);
      }
    }
    __syncthreads();
    // G = C . B^T  (wave owns rows [wave*16, wave*16+16))
    f32x4 accG[4] = {};
    #pragma unroll
    for (int kk = 0; kk < 2; ++kk){
      const int kb = (kk<<5) + (hi<<3);
      const int rA = (wave<<4) + lo16;
      const bf16x8 a = *(const bf16x8*)&Cn[(rA<<6) + (kb ^ ((rA&7)<<3))];
      #pragma unroll
      for (int t = 0; t < 4; ++t){
        const int rb = (t<<4) + lo16;
        const bf16x8 bb = *(const bf16x8*)&Bn[(rb<<6) + (kb ^ ((rb&7)<<3))];
        accG[t] = __builtin_amdgcn_mfma_f32_16x16x32_bf16(a, bb, accG[t], 0,0,0);
      }
    }
    // M = mask(G) * exp(Acs[r]-Acs[s])  -> wave-private rows, no barrier needed
    #pragma unroll
    for (int t = 0; t < 4; ++t)
    #pragma unroll
    for (int i = 0; i < 4; ++i){
      const int r = (wave<<4) + (hi<<2) + i;
      const int s = (t<<4) + lo16;
      const float v = (s <= r) ? accG[t][i] * __expf(Acs[r] - Acs[s]) : 0.f;
      Ml[swz(r,s)] = f2bf(v);
    }
    // Y = M.xdt + Cd.S^T ;  S_chunk = xdtT.(dec*B)
    f32x4 accY[4] = {}, accS[4] = {};
    #pragma unroll
    for (int kk = 0; kk < 2; ++kk){
      const int kb = (kk<<5) + (hi<<3);
      const int rA = (wave<<4) + lo16;
      const int oA = (rA<<6) + (kb ^ ((rA&7)<<3));
      const bf16x8 aM = *(const bf16x8*)&Ml[oA];
      const bf16x8 aC = *(const bf16x8*)&Cd[oA];
      const bf16x8 aX = *(const bf16x8*)&xdtT[oA];
      #pragma unroll
      for (int t = 0; t < 4; ++t){
        const int rb = (t<<4) + lo16;
        const int o = (rb<<6) + (kb ^ ((rb&7)<<3));
        const bf16x8 bX = *(const bf16x8*)&xdtT[o];
        const bf16x8 bS = *(const bf16x8*)&Sbf[o];
        const bf16x8 bB = *(const bf16x8*)&Bdt[o];
        accY[t] = __builtin_amdgcn_mfma_f32_16x16x32_bf16(aM, bX, accY[t], 0,0,0);
        accY[t] = __builtin_amdgcn_mfma_f32_16x16x32_bf16(aC, bS, accY[t], 0,0,0);
        accS[t] = __builtin_amdgcn_mfma_f32_16x16x32_bf16(aX, bB, accS[t], 0,0,0);
      }
    }
    __syncthreads();   // all waves done reading Sbf before update
    const float lam = __expf(Alast);
    #pragma unroll
    for (int t = 0; t < 4; ++t)
    #pragma unroll
    for (int i = 0; i < 4; ++i){
      const int p = (wave<<4) + (hi<<2) + i;
      const int n = (t<<4) + lo16;
      const float s = Sst[(p<<6)+n] * lam + accS[t][i];
      Sst[(p<<6)+n] = s;
      Sbf[swz(p,n)] = f2bf(s);
    }
    #pragma unroll
    for (int t = 0; t < 4; ++t)
    #pragma unroll
    for (int i = 0; i < 4; ++i){
      const int r = (wave<<4) + (hi<<2) + i;
      const int p = (t<<4) + lo16;
      const float y = accY[t][i] + bf2f(xls[swz(r,p)]) * Dh;
      yo[bx + (size_t)(l0+r)*1536 + p] = f2bf(y);
    }
  }
}

// ---------------- gate (silu(z)) + RMS norm ----------------
__global__ __launch_bounds__(192) void k_gnorm(
    const u16* __restrict__ y, const u16* __restrict__ z,
    const float* __restrict__ nw, u16* __restrict__ out)
{
  __shared__ float red[3];
  const int m = blockIdx.x, t = threadIdx.x;
  const size_t base = (size_t)m*1536 + t*8;
  const u16x8 yv = *(const u16x8*)(y + base);
  const u16x8 zv = *(const u16x8*)(z + base);
  float vals[8]; float ss = 0.f;
  #pragma unroll
  for (int j = 0; j < 8; ++j){
    const float zf = bf2f(zv[j]);
    const float v = bf2f(yv[j]) * zf / (1.f + __expf(-zf));
    vals[j] = v; ss += v*v;
  }
  #pragma unroll
  for (int off = 32; off > 0; off >>= 1) ss += __shfl_down(ss, off);
  if ((t & 63) == 0) red[t>>6] = ss;
  __syncthreads();
  const float sc = rsqrtf((red[0]+red[1]+red[2]) * (1.f/1536.f) + 1e-5f);
  u16x8 o;
  #pragma unroll
  for (int j = 0; j < 8; ++j) o[j] = f2bf(vals[j] * sc * nw[t*8+j]);
  *(u16x8*)(out + base) = o;
}

extern "C" void kernel_launch(void* const* d_in, const int* in_sizes, int n_in,
                              void* d_out, int out_size, void* d_ws, size_t ws_size,
                              hipStream_t stream)
{
  const float* u       = (const float*)d_in[0];
  const float* W_in    = (const float*)d_in[1];
  const float* conv_w  = (const float*)d_in[2];
  const float* conv_b  = (const float*)d_in[3];
  const float* dt_bias = (const float*)d_in[4];
  const float* A_log   = (const float*)d_in[5];
  const float* D_param = (const float*)d_in[6];
  const float* norm_w  = (const float*)d_in[7];
  const float* W_out   = (const float*)d_in[8];
  (void)in_sizes; (void)n_in; (void)out_size;
  if (ws_size < (size_t)379715584) return;   // clean fail instead of corruption

  char* w = (char*)d_ws;
  size_t off = 0;
  auto alloc = [&](size_t bytes)->void*{ void* p = w + off; off += (bytes + 255) & ~(size_t)255; return p; };
  u16* ubf    = (u16*)alloc(50331648);    // 32768x768 bf16
  u16* winbf  = (u16*)alloc(5111808);     // 3328x768 bf16 (padded)
  u16* woutbf = (u16*)alloc(2359296);     // 768x1536 bf16
  u16* zbf    = (u16*)alloc(100663296);   // 32768x1536 bf16
  u16* xbcbf  = (u16*)alloc(109051904);   // 32768x1664 bf16 (reused as yssd)
  float* dtbuf= (float*)alloc(3145728);   // 32768x24 f32
  u16* xconv  = (u16*)alloc(100663296);   // 32768x1536 bf16 (reused as ynorm)
  u16* Bbuf   = (u16*)alloc(4194304);     // 32768x64 bf16
  u16* Cbuf   = (u16*)alloc(4194304);     // 32768x64 bf16
  u16* yssd   = xbcbf;
  u16* ynorm  = xconv;

  k_cast<<<24576, 256, 0, stream>>>(u, ubf, 6291456);
  k_cast_pad<<<2496, 256, 0, stream>>>(W_in, winbf);
  k_cast<<<1152, 256, 0, stream>>>(W_out, woutbf, 294912);
  k_gemm<768,0><<<dim3(256,26), 256, 0, stream>>>(ubf, winbf, zbf, xbcbf, dtbuf, dt_bias, nullptr);
  k_conv<<<3328, 256, 0, stream>>>(xbcbf, conv_w, conv_b, xconv, Bbuf, Cbuf);
  k_ssd<<<192, 256, 0, stream>>>(xconv, Bbuf, Cbuf, dtbuf, A_log, D_param, yssd);
  k_gnorm<<<32768, 192, 0, stream>>>(yssd, zbf, norm_w, ynorm);
  k_gemm<1536,1><<<dim3(256,6), 256, 0, stream>>>(ynorm, woutbf, nullptr, nullptr, nullptr, nullptr, (float*)d_out);
}